// Round 2
// baseline (4424.292 us; speedup 1.0000x reference)
//
#include <hip/hip_runtime.h>
#include <math.h>

typedef _Float16 f16;
typedef f16  f16x4  __attribute__((ext_vector_type(4)));
typedef f16  f16x8  __attribute__((ext_vector_type(8)));
typedef float f32x16 __attribute__((ext_vector_type(16)));

constexpr int T  = 16384;
constexpr int D  = 7168;
constexpr int E  = 256;
constexpr int NG = 8;
constexpr int GS = 32;
constexpr int TOPK_G = 4;
constexpr int TOPK   = 8;

constexpr float W_SCALE     = 256.0f;   // keeps w_lo out of fp16 subnormals
constexpr float INV_W_SCALE = 1.0f / 256.0f;
constexpr float EPS_GAP     = 2e-5f;    // score-domain near-tie band -> fixup

constexpr int FNT = 8;                  // fixup: tokens per batch (W reused 8x)
constexpr int CK  = 128;                // fixup: staged X floats per token per chunk

// workspace layout
constexpr size_t WS_CNT    = 0;                       // int counter
constexpr size_t WS_LIST   = 64;                      // int[16384] flagged tokens
constexpr size_t WS_BPACK  = 131072;                  // f16 frags of W (hi/lo)
constexpr size_t BPACK_ELEMS = (size_t)448 * 8 * 2 * 512;   // k16 x tileN x part x (64 lanes x 8)
constexpr size_t WS_NEEDED = WS_BPACK + BPACK_ELEMS * sizeof(f16);

// ---------------------------------------------------------------------------
// shared routing: sc[256] = sigmoid scores (destroyed). Writes weights+indices,
// returns min decision gap (group 4/5 boundary + all adjacent top-8/9 gaps).
// ---------------------------------------------------------------------------
__device__ float route_row(float* sc, float* ow, float* oi) {
    float gmax[NG];
#pragma unroll
    for (int g = 0; g < NG; ++g) {
        float m = sc[g * GS];
        for (int j = 1; j < GS; ++j) m = fmaxf(m, sc[g * GS + j]);
        gmax[g] = m;
    }
    // top-4 groups (strict >, ascending scan = lower-index tie-break) + 5th for gap
    int cmask = 0;
    float top5[5];
#pragma unroll
    for (int it = 0; it < 5; ++it) {
        float best = -INFINITY; int bg = 0;
#pragma unroll
        for (int g = 0; g < NG; ++g) {
            if (!((cmask >> g) & 1) && gmax[g] > best) { best = gmax[g]; bg = g; }
        }
        top5[it] = best;
        if (it < TOPK_G) cmask |= (1 << bg);
    }
    const float gap45 = top5[3] - top5[4];
    // mask non-chosen groups
#pragma unroll
    for (int g = 0; g < NG; ++g) {
        if (!((cmask >> g) & 1)) {
            for (int j = 0; j < GS; ++j) sc[g * GS + j] = -INFINITY;
        }
    }
    // top-9 selection (9th value only for the 8/9 gap)
    float vals[TOPK + 1]; int idxs[TOPK + 1];
    for (int it = 0; it < TOPK + 1; ++it) {
        float best = -INFINITY; int bi = 0;
        for (int e = 0; e < E; ++e) {
            const float v = sc[e];
            if (v > best) { best = v; bi = e; }
        }
        vals[it] = best; idxs[it] = bi; sc[bi] = -INFINITY;
    }
    float mingap = gap45;
#pragma unroll
    for (int i = 0; i < TOPK; ++i) mingap = fminf(mingap, vals[i] - vals[i + 1]);

    float s = 0.0f;
#pragma unroll
    for (int k = 0; k < TOPK; ++k) s += vals[k];
    const float scale = 2.5f / s;
#pragma unroll
    for (int k = 0; k < TOPK; ++k) { ow[k] = vals[k] * scale; oi[k] = (float)idxs[k]; }
    return mingap;
}

// ---------------------------------------------------------------------------
// Phase 0: zero the flag counter (ws is poisoned 0xAA before every launch)
// ---------------------------------------------------------------------------
__global__ void zero_cnt(int* c) { if (threadIdx.x == 0) *c = 0; }

// ---------------------------------------------------------------------------
// Phase 1: pack W -> fp16 hi/lo MFMA B-fragments (scaled by 256).
// B frag (32x32x16): lane holds col n=lane&31, k=(lane>>5)*8 + j (j=0..7).
// Layout: Bp[((k16*8 + tileN)*2 + part)*512 + lane*8 + j]
// ---------------------------------------------------------------------------
__global__ __launch_bounds__(256)
void pack_w(const float* __restrict__ W, f16* __restrict__ Bp) {
    const int gid  = blockIdx.x * 256 + threadIdx.x;   // < 448*8*64
    const int lane = gid & 63;
    const int f    = gid >> 6;          // k16*8 + tileN
    const int k16  = f >> 3;
    const int tn   = f & 7;
    const int e    = tn * 32 + (lane & 31);
    const int kb   = k16 * 16 + (lane >> 5) * 8;
    const float* wp = W + (size_t)e * D + kb;
    const float4 v0 = *(const float4*)wp;
    const float4 v1 = *(const float4*)(wp + 4);
    float vv[8] = {v0.x, v0.y, v0.z, v0.w, v1.x, v1.y, v1.z, v1.w};
    f16x8 h, l;
#pragma unroll
    for (int j = 0; j < 8; ++j) {
        const float s = vv[j] * W_SCALE;
        const f16 hh = (f16)s;
        h[j] = hh;
        l[j] = (f16)(s - (float)hh);
    }
    f16* dst = Bp + (size_t)f * 1024 + lane * 8;
    *(f16x8*)dst         = h;
    *(f16x8*)(dst + 512) = l;
}

// ---------------------------------------------------------------------------
// Phase 2: main GEMM (split-fp16, 3-product MFMA 32x32x16) + routing + flagging
// 512 threads = 8 waves; wave w owns col tile w (32 experts), rows 0..63.
// ---------------------------------------------------------------------------
__global__ __launch_bounds__(512, 2)
void gate_mfma(const float* __restrict__ X, const f16* __restrict__ Bp,
               float* __restrict__ out, int* __restrict__ cnt, int* __restrict__ list) {
    // A fragments in LDS: [buf][k16half][tileM][part hi/lo][lane][j]  (16 KB)
    __shared__ f16 Ahl[2][2][2][2][64][8];
    __shared__ float Sc[64 * 257];   // 65.8 KB score tile, stride 257

    const int tid  = threadIdx.x;
    const int lane = tid & 63;
    const int wv   = tid >> 6;            // 0..7 -> col tile
    const int row0 = blockIdx.x * 64;

    // ---- A staging mapping (X fp32 -> fp16 hi/lo frags) ----
    const int srow  = tid >> 3;           // 0..63
    const int sq    = tid & 7;            // k-quad: k_local = sq*4..+3
    const int s_kh  = sq >> 2;            // which k16 half of the 32-chunk
    const int s_ks  = (sq & 3) * 4;       // 0,4,8,12 within k16
    const int s_lane = (srow & 31) + ((s_ks >> 3) << 5);
    const int s_j   = s_ks & 7;           // 0 or 4
    const int s_tile = srow >> 5;

    const float* xp = X + (size_t)(row0 + srow) * D + sq * 4;

    // B frag pointer: per chunk (32 k = 2 k16): stride 2*8192 elems
    const f16* bptr = Bp + (size_t)wv * 1024 + (size_t)lane * 8;

    f32x16 acc0, acc1;
#pragma unroll
    for (int r = 0; r < 16; ++r) { acc0[r] = 0.0f; acc1[r] = 0.0f; }

    // preload chunk 0
    float4 xv = *(const float4*)xp; xp += 32;
    f16x8 bh0 = *(const f16x8*)(bptr + 0);
    f16x8 bl0 = *(const f16x8*)(bptr + 512);
    f16x8 bh1 = *(const f16x8*)(bptr + 8192);
    f16x8 bl1 = *(const f16x8*)(bptr + 8704);
    bptr += 16384;

    // stage chunk 0 into buf 0
    {
        f16x4 h, l;
        const float* v = (const float*)&xv;
#pragma unroll
        for (int u = 0; u < 4; ++u) {
            const f16 hh = (f16)v[u];
            h[u] = hh; l[u] = (f16)(v[u] - (float)hh);
        }
        *(f16x4*)&Ahl[0][s_kh][s_tile][0][s_lane][s_j] = h;
        *(f16x4*)&Ahl[0][s_kh][s_tile][1][s_lane][s_j] = l;
    }
    __syncthreads();

    constexpr int NCH = D / 32;   // 224
    int buf = 0;
    for (int c = 0; c < NCH; ++c) {
        const bool has_next = (c + 1 < NCH);
        float4 xn;
        f16x8 nbh0, nbl0, nbh1, nbl1;
        if (has_next) {
            xn   = *(const float4*)xp; xp += 32;
            nbh0 = *(const f16x8*)(bptr + 0);
            nbl0 = *(const f16x8*)(bptr + 512);
            nbh1 = *(const f16x8*)(bptr + 8192);
            nbl1 = *(const f16x8*)(bptr + 8704);
            bptr += 16384;
        }
        // ---- compute from LDS buf + current B regs ----
        {
            const f16x8 a0h = *(const f16x8*)&Ahl[buf][0][0][0][lane][0];
            const f16x8 a0l = *(const f16x8*)&Ahl[buf][0][0][1][lane][0];
            const f16x8 a1h = *(const f16x8*)&Ahl[buf][0][1][0][lane][0];
            const f16x8 a1l = *(const f16x8*)&Ahl[buf][0][1][1][lane][0];
            acc0 = __builtin_amdgcn_mfma_f32_32x32x16_f16(a0h, bh0, acc0, 0, 0, 0);
            acc1 = __builtin_amdgcn_mfma_f32_32x32x16_f16(a1h, bh0, acc1, 0, 0, 0);
            acc0 = __builtin_amdgcn_mfma_f32_32x32x16_f16(a0h, bl0, acc0, 0, 0, 0);
            acc1 = __builtin_amdgcn_mfma_f32_32x32x16_f16(a1h, bl0, acc1, 0, 0, 0);
            acc0 = __builtin_amdgcn_mfma_f32_32x32x16_f16(a0l, bh0, acc0, 0, 0, 0);
            acc1 = __builtin_amdgcn_mfma_f32_32x32x16_f16(a1l, bh0, acc1, 0, 0, 0);
        }
        {
            const f16x8 a0h = *(const f16x8*)&Ahl[buf][1][0][0][lane][0];
            const f16x8 a0l = *(const f16x8*)&Ahl[buf][1][0][1][lane][0];
            const f16x8 a1h = *(const f16x8*)&Ahl[buf][1][1][0][lane][0];
            const f16x8 a1l = *(const f16x8*)&Ahl[buf][1][1][1][lane][0];
            acc0 = __builtin_amdgcn_mfma_f32_32x32x16_f16(a0h, bh1, acc0, 0, 0, 0);
            acc1 = __builtin_amdgcn_mfma_f32_32x32x16_f16(a1h, bh1, acc1, 0, 0, 0);
            acc0 = __builtin_amdgcn_mfma_f32_32x32x16_f16(a0h, bl1, acc0, 0, 0, 0);
            acc1 = __builtin_amdgcn_mfma_f32_32x32x16_f16(a1h, bl1, acc1, 0, 0, 0);
            acc0 = __builtin_amdgcn_mfma_f32_32x32x16_f16(a0l, bh1, acc0, 0, 0, 0);
            acc1 = __builtin_amdgcn_mfma_f32_32x32x16_f16(a1l, bh1, acc1, 0, 0, 0);
        }
        // ---- stage next chunk into the other buffer ----
        if (has_next) {
            f16x4 h, l;
            const float* v = (const float*)&xn;
#pragma unroll
            for (int u = 0; u < 4; ++u) {
                const f16 hh = (f16)v[u];
                h[u] = hh; l[u] = (f16)(v[u] - (float)hh);
            }
            *(f16x4*)&Ahl[buf ^ 1][s_kh][s_tile][0][s_lane][s_j] = h;
            *(f16x4*)&Ahl[buf ^ 1][s_kh][s_tile][1][s_lane][s_j] = l;
            bh0 = nbh0; bl0 = nbl0; bh1 = nbh1; bl1 = nbl1;
        }
        __syncthreads();
        buf ^= 1;
    }

    // ---- epilogue: C/D layout col=lane&31, row=(r&3)+8*(r>>2)+4*(lane>>5) ----
    const int ccol  = wv * 32 + (lane & 31);
    const int rbase = 4 * (lane >> 5);
#pragma unroll
    for (int r = 0; r < 16; ++r) {
        const int rw = (r & 3) + 8 * (r >> 2) + rbase;
        Sc[rw * 257 + ccol]        = acc0[r];
        Sc[(rw + 32) * 257 + ccol] = acc1[r];
    }
    __syncthreads();

    // ---- routing: one lane per row ----
    if (tid < 64) {
        float* sc = &Sc[tid * 257];
        for (int e = 0; e < E; ++e)
            sc[e] = 1.0f / (1.0f + expf(-sc[e] * INV_W_SCALE));
        const int token = row0 + tid;
        const float mingap = route_row(sc, out + (size_t)token * TOPK,
                                       out + (size_t)T * TOPK + (size_t)token * TOPK);
        if (mingap < EPS_GAP) {
            const int s = atomicAdd(cnt, 1);
            if (s < T) list[s] = token;
        }
    }
}

// ---------------------------------------------------------------------------
// Phase 3: exact fp32 recompute + routing for flagged (near-tie) tokens.
// Token-BATCHED (W streamed once per FNT tokens) with LDS-STAGED X:
//  - X chunks (CK floats x FNT tokens) staged coalesced, double-buffered
//    (fixes round-1 regression: per-lane global broadcast loads stalled the
//    single wave/SIMD; LDS broadcast reads are ~5cy vs ~500cy global).
//  - Per-expert summation order (sequential 64-float c2 chunks over full D,
//    identical FMA expression) EXACTLY matches the original fixup.
// ---------------------------------------------------------------------------
__global__ __launch_bounds__(256, 2)
void gate_fixup(const float* __restrict__ X, const float* __restrict__ W,
                float* __restrict__ out, const int* __restrict__ cnt,
                const int* __restrict__ list) {
    __shared__ float xs[2][FNT][CK];    // 8 KB double-buffered X chunks
    __shared__ float sc[FNT][E + 1];    // 8.2 KB scores
    int n = *cnt; if (n > T) n = T;
    if (n <= 0) return;
    const int e = threadIdx.x;
    const float* wr = W + (size_t)e * D;
    const int stok = threadIdx.x >> 5;            // staging token slot 0..7
    const int sf4  = (threadIdx.x & 31) << 2;     // float offset 0..124

    for (int base = blockIdx.x * FNT; base < n; base += gridDim.x * FNT) {
        // staging pointer for this thread's token (clamped tail -> duplicate work)
        int sidx = base + stok; if (sidx > n - 1) sidx = n - 1;
        const float* sxr = X + (size_t)list[sidx] * D + sf4;

        // stage chunk 0
        *(float4*)&xs[0][stok][sf4] = *(const float4*)&sxr[0];
        __syncthreads();

        float acc[FNT];
#pragma unroll
        for (int t = 0; t < FNT; ++t) acc[t] = 0.0f;

        int buf = 0;
        for (int c0 = 0; c0 < D; c0 += CK) {
            const bool has_next = (c0 + CK < D);
            float4 nx;
            if (has_next) nx = *(const float4*)&sxr[c0 + CK];
            // two 64-float c2 sub-chunks per staged chunk (original order)
#pragma unroll
            for (int h = 0; h < 2; ++h) {
                float c2[FNT];
#pragma unroll
                for (int t = 0; t < FNT; ++t) c2[t] = 0.0f;
#pragma unroll
                for (int k = 0; k < 64; k += 4) {
                    const float4 wv = *(const float4*)&wr[c0 + h * 64 + k];
#pragma unroll
                    for (int t = 0; t < FNT; ++t) {
                        const float4 xv = *(const float4*)&xs[buf][t][h * 64 + k];
                        c2[t] += xv.x * wv.x + xv.y * wv.y + xv.z * wv.z + xv.w * wv.w;
                    }
                }
#pragma unroll
                for (int t = 0; t < FNT; ++t) acc[t] += c2[t];
            }
            if (has_next) *(float4*)&xs[buf ^ 1][stok][sf4] = nx;
            __syncthreads();
            buf ^= 1;
        }

        // scores -> sc, then route FNT tokens with FNT threads
#pragma unroll
        for (int t = 0; t < FNT; ++t)
            sc[t][e] = 1.0f / (1.0f + expf(-acc[t]));
        __syncthreads();
        if (e < FNT && base + e < n) {
            const int tok = list[base + e];
            route_row(&sc[e][0], out + (size_t)tok * TOPK,
                      out + (size_t)T * TOPK + (size_t)tok * TOPK);
        }
        __syncthreads();
    }
}

// ---------------------------------------------------------------------------
// Fallback (round-2 fp32 vector kernel) if ws is too small for Bpack
// ---------------------------------------------------------------------------
__global__ __launch_bounds__(256, 2)
void gate_fused_fp32(const float* __restrict__ X, const float* __restrict__ W,
                     float* __restrict__ out) {
    constexpr int BM = 32, BK = 16, AS_S = 36, BS_S = 260, SC_S = 257;
    __shared__ float As[BK * AS_S];
    __shared__ float Bs[BK * BS_S];
    __shared__ float Sc[BM * SC_S];

    const int tid  = threadIdx.x;
    const int row0 = blockIdx.x * BM;
    const int lrow = tid >> 2;
    const int kq4  = (tid & 3) << 2;
    const bool a_loader = (tid < 128);

    const float* aptr = X + (size_t)(row0 + (lrow & 31)) * D + kq4;
    const float* bptr = W + (size_t)lrow * D + kq4;
    const int ty = tid >> 5, tx = tid & 31;

    float acc[4][8];
#pragma unroll
    for (int i = 0; i < 4; ++i)
#pragma unroll
        for (int j = 0; j < 8; ++j) acc[i][j] = 0.0f;

    float4 areg;
    if (a_loader) areg = *(const float4*)aptr;
    float4 breg0 = *(const float4*)(bptr);
    float4 breg1 = *(const float4*)(bptr + (size_t)64 * D);
    float4 breg2 = *(const float4*)(bptr + (size_t)128 * D);
    float4 breg3 = *(const float4*)(bptr + (size_t)192 * D);
    aptr += BK; bptr += BK;

    constexpr int NKT = D / BK;
    for (int kt = 0; kt < NKT; ++kt) {
        __syncthreads();
        {
            const float* b0 = (const float*)&breg0;
            const float* b1 = (const float*)&breg1;
            const float* b2 = (const float*)&breg2;
            const float* b3 = (const float*)&breg3;
#pragma unroll
            for (int j = 0; j < 4; ++j) {
                Bs[(kq4 + j) * BS_S + lrow]       = b0[j];
                Bs[(kq4 + j) * BS_S + 64 + lrow]  = b1[j];
                Bs[(kq4 + j) * BS_S + 128 + lrow] = b2[j];
                Bs[(kq4 + j) * BS_S + 192 + lrow] = b3[j];
            }
            if (a_loader) {
                const float* a = (const float*)&areg;
#pragma unroll
                for (int j = 0; j < 4; ++j)
                    As[(kq4 + j) * AS_S + (lrow & 31)] = a[j];
            }
        }
        __syncthreads();
        if (kt + 1 < NKT) {
            if (a_loader) areg = *(const float4*)aptr;
            breg0 = *(const float4*)(bptr);
            breg1 = *(const float4*)(bptr + (size_t)64 * D);
            breg2 = *(const float4*)(bptr + (size_t)128 * D);
            breg3 = *(const float4*)(bptr + (size_t)192 * D);
            aptr += BK; bptr += BK;
        }
        float c2[4][8];
#pragma unroll
        for (int k = 0; k < BK; ++k) {
            float af[4], bf[8];
            *(float4*)&af[0] = *(const float4*)&As[k * AS_S + (ty << 2)];
            *(float4*)&bf[0] = *(const float4*)&Bs[k * BS_S + (tx << 2)];
            *(float4*)&bf[4] = *(const float4*)&Bs[k * BS_S + 128 + (tx << 2)];
#pragma unroll
            for (int i = 0; i < 4; ++i)
#pragma unroll
                for (int j = 0; j < 8; ++j) {
                    if (k == 0) c2[i][j] = af[i] * bf[j];
                    else        c2[i][j] += af[i] * bf[j];
                }
        }
#pragma unroll
        for (int i = 0; i < 4; ++i)
#pragma unroll
            for (int j = 0; j < 8; ++j) acc[i][j] += c2[i][j];
    }

    __syncthreads();
#pragma unroll
    for (int i = 0; i < 4; ++i) {
        const int r = (ty << 2) + i;
#pragma unroll
        for (int j = 0; j < 8; ++j) {
            const int c = (j < 4) ? ((tx << 2) + j) : (128 + (tx << 2) + j - 4);
            Sc[r * SC_S + c] = acc[i][j];
        }
    }
    __syncthreads();

    if (tid < BM) {
        float* sc = &Sc[tid * SC_S];
        for (int e = 0; e < E; ++e) sc[e] = 1.0f / (1.0f + expf(-sc[e]));
        const int token = row0 + tid;
        route_row(sc, out + (size_t)token * TOPK,
                  out + (size_t)T * TOPK + (size_t)token * TOPK);
    }
}

extern "C" void kernel_launch(void* const* d_in, const int* in_sizes, int n_in,
                              void* d_out, int out_size, void* d_ws, size_t ws_size,
                              hipStream_t stream) {
    const float* x = (const float*)d_in[0];
    const float* w = (const float*)d_in[1];
    float* out = (float*)d_out;
    (void)in_sizes; (void)n_in; (void)out_size;

    if (ws_size >= WS_NEEDED) {
        int* cnt   = (int*)((char*)d_ws + WS_CNT);
        int* list  = (int*)((char*)d_ws + WS_LIST);
        f16* bpack = (f16*)((char*)d_ws + WS_BPACK);
        zero_cnt<<<1, 64, 0, stream>>>(cnt);
        pack_w<<<896, 256, 0, stream>>>(w, bpack);
        gate_mfma<<<T / 64, 512, 0, stream>>>(x, bpack, out, cnt, list);
        gate_fixup<<<512, 256, 0, stream>>>(x, w, out, cnt, list);
    } else {
        gate_fused_fp32<<<T / 32, 256, 0, stream>>>(x, w, out);
    }
}

// Round 3
// 1187.179 us; speedup vs baseline: 3.7267x; 3.7267x over previous
//
#include <hip/hip_runtime.h>
#include <math.h>

typedef _Float16 f16;
typedef f16  f16x4  __attribute__((ext_vector_type(4)));
typedef f16  f16x8  __attribute__((ext_vector_type(8)));
typedef float f32x16 __attribute__((ext_vector_type(16)));

constexpr int T  = 16384;
constexpr int D  = 7168;
constexpr int E  = 256;
constexpr int NG = 8;
constexpr int GS = 32;
constexpr int TOPK_G = 4;
constexpr int TOPK   = 8;

constexpr float W_SCALE     = 256.0f;   // keeps w_lo out of fp16 subnormals
constexpr float INV_W_SCALE = 1.0f / 256.0f;
constexpr float EPS_GAP     = 2e-5f;    // score-domain near-tie band -> fixup

constexpr int FNT = 4;                  // fixup: tokens per batch (W reused 4x)

// workspace layout
constexpr size_t WS_CNT    = 0;                       // int counter
constexpr size_t WS_LIST   = 64;                      // int[16384] flagged tokens
constexpr size_t WS_BPACK  = 131072;                  // f16 frags of W (hi/lo)
constexpr size_t BPACK_ELEMS = (size_t)448 * 8 * 2 * 512;   // k16 x tileN x part x (64 lanes x 8)
constexpr size_t WS_NEEDED = WS_BPACK + BPACK_ELEMS * sizeof(f16);

// ---------------------------------------------------------------------------
// shared routing: sc[256] = sigmoid scores (destroyed). Writes weights+indices,
// returns min decision gap (group 4/5 boundary + all adjacent top-8/9 gaps).
// ---------------------------------------------------------------------------
__device__ float route_row(float* sc, float* ow, float* oi) {
    float gmax[NG];
#pragma unroll
    for (int g = 0; g < NG; ++g) {
        float m = sc[g * GS];
        for (int j = 1; j < GS; ++j) m = fmaxf(m, sc[g * GS + j]);
        gmax[g] = m;
    }
    // top-4 groups (strict >, ascending scan = lower-index tie-break) + 5th for gap
    int cmask = 0;
    float top5[5];
#pragma unroll
    for (int it = 0; it < 5; ++it) {
        float best = -INFINITY; int bg = 0;
#pragma unroll
        for (int g = 0; g < NG; ++g) {
            if (!((cmask >> g) & 1) && gmax[g] > best) { best = gmax[g]; bg = g; }
        }
        top5[it] = best;
        if (it < TOPK_G) cmask |= (1 << bg);
    }
    const float gap45 = top5[3] - top5[4];
    // mask non-chosen groups
#pragma unroll
    for (int g = 0; g < NG; ++g) {
        if (!((cmask >> g) & 1)) {
            for (int j = 0; j < GS; ++j) sc[g * GS + j] = -INFINITY;
        }
    }
    // top-9 selection (9th value only for the 8/9 gap)
    float vals[TOPK + 1]; int idxs[TOPK + 1];
    for (int it = 0; it < TOPK + 1; ++it) {
        float best = -INFINITY; int bi = 0;
        for (int e = 0; e < E; ++e) {
            const float v = sc[e];
            if (v > best) { best = v; bi = e; }
        }
        vals[it] = best; idxs[it] = bi; sc[bi] = -INFINITY;
    }
    float mingap = gap45;
#pragma unroll
    for (int i = 0; i < TOPK; ++i) mingap = fminf(mingap, vals[i] - vals[i + 1]);

    float s = 0.0f;
#pragma unroll
    for (int k = 0; k < TOPK; ++k) s += vals[k];
    const float scale = 2.5f / s;
#pragma unroll
    for (int k = 0; k < TOPK; ++k) { ow[k] = vals[k] * scale; oi[k] = (float)idxs[k]; }
    return mingap;
}

// ---------------------------------------------------------------------------
// Phase 0: zero the flag counter (ws is poisoned 0xAA before every launch)
// ---------------------------------------------------------------------------
__global__ void zero_cnt(int* c) { if (threadIdx.x == 0) *c = 0; }

// ---------------------------------------------------------------------------
// Phase 1: pack W -> fp16 hi/lo MFMA B-fragments (scaled by 256).
// B frag (32x32x16): lane holds col n=lane&31, k=(lane>>5)*8 + j (j=0..7).
// Layout: Bp[((k16*8 + tileN)*2 + part)*512 + lane*8 + j]
// ---------------------------------------------------------------------------
__global__ __launch_bounds__(256)
void pack_w(const float* __restrict__ W, f16* __restrict__ Bp) {
    const int gid  = blockIdx.x * 256 + threadIdx.x;   // < 448*8*64
    const int lane = gid & 63;
    const int f    = gid >> 6;          // k16*8 + tileN
    const int k16  = f >> 3;
    const int tn   = f & 7;
    const int e    = tn * 32 + (lane & 31);
    const int kb   = k16 * 16 + (lane >> 5) * 8;
    const float* wp = W + (size_t)e * D + kb;
    const float4 v0 = *(const float4*)wp;
    const float4 v1 = *(const float4*)(wp + 4);
    float vv[8] = {v0.x, v0.y, v0.z, v0.w, v1.x, v1.y, v1.z, v1.w};
    f16x8 h, l;
#pragma unroll
    for (int j = 0; j < 8; ++j) {
        const float s = vv[j] * W_SCALE;
        const f16 hh = (f16)s;
        h[j] = hh;
        l[j] = (f16)(s - (float)hh);
    }
    f16* dst = Bp + (size_t)f * 1024 + lane * 8;
    *(f16x8*)dst         = h;
    *(f16x8*)(dst + 512) = l;
}

// ---------------------------------------------------------------------------
// Phase 2: main GEMM (split-fp16, 3-product MFMA 32x32x16) + routing + flagging
// 512 threads = 8 waves; wave w owns col tile w (32 experts), rows 0..63.
// ---------------------------------------------------------------------------
__global__ __launch_bounds__(512, 2)
void gate_mfma(const float* __restrict__ X, const f16* __restrict__ Bp,
               float* __restrict__ out, int* __restrict__ cnt, int* __restrict__ list) {
    // A fragments in LDS: [buf][k16half][tileM][part hi/lo][lane][j]  (16 KB)
    __shared__ f16 Ahl[2][2][2][2][64][8];
    __shared__ float Sc[64 * 257];   // 65.8 KB score tile, stride 257

    const int tid  = threadIdx.x;
    const int lane = tid & 63;
    const int wv   = tid >> 6;            // 0..7 -> col tile
    const int row0 = blockIdx.x * 64;

    // ---- A staging mapping (X fp32 -> fp16 hi/lo frags) ----
    const int srow  = tid >> 3;           // 0..63
    const int sq    = tid & 7;            // k-quad: k_local = sq*4..+3
    const int s_kh  = sq >> 2;            // which k16 half of the 32-chunk
    const int s_ks  = (sq & 3) * 4;       // 0,4,8,12 within k16
    const int s_lane = (srow & 31) + ((s_ks >> 3) << 5);
    const int s_j   = s_ks & 7;           // 0 or 4
    const int s_tile = srow >> 5;

    const float* xp = X + (size_t)(row0 + srow) * D + sq * 4;

    // B frag pointer: per chunk (32 k = 2 k16): stride 2*8192 elems
    const f16* bptr = Bp + (size_t)wv * 1024 + (size_t)lane * 8;

    f32x16 acc0, acc1;
#pragma unroll
    for (int r = 0; r < 16; ++r) { acc0[r] = 0.0f; acc1[r] = 0.0f; }

    // preload chunk 0
    float4 xv = *(const float4*)xp; xp += 32;
    f16x8 bh0 = *(const f16x8*)(bptr + 0);
    f16x8 bl0 = *(const f16x8*)(bptr + 512);
    f16x8 bh1 = *(const f16x8*)(bptr + 8192);
    f16x8 bl1 = *(const f16x8*)(bptr + 8704);
    bptr += 16384;

    // stage chunk 0 into buf 0
    {
        f16x4 h, l;
        const float* v = (const float*)&xv;
#pragma unroll
        for (int u = 0; u < 4; ++u) {
            const f16 hh = (f16)v[u];
            h[u] = hh; l[u] = (f16)(v[u] - (float)hh);
        }
        *(f16x4*)&Ahl[0][s_kh][s_tile][0][s_lane][s_j] = h;
        *(f16x4*)&Ahl[0][s_kh][s_tile][1][s_lane][s_j] = l;
    }
    __syncthreads();

    constexpr int NCH = D / 32;   // 224
    int buf = 0;
    for (int c = 0; c < NCH; ++c) {
        const bool has_next = (c + 1 < NCH);
        float4 xn;
        f16x8 nbh0, nbl0, nbh1, nbl1;
        if (has_next) {
            xn   = *(const float4*)xp; xp += 32;
            nbh0 = *(const f16x8*)(bptr + 0);
            nbl0 = *(const f16x8*)(bptr + 512);
            nbh1 = *(const f16x8*)(bptr + 8192);
            nbl1 = *(const f16x8*)(bptr + 8704);
            bptr += 16384;
        }
        // ---- compute from LDS buf + current B regs ----
        {
            const f16x8 a0h = *(const f16x8*)&Ahl[buf][0][0][0][lane][0];
            const f16x8 a0l = *(const f16x8*)&Ahl[buf][0][0][1][lane][0];
            const f16x8 a1h = *(const f16x8*)&Ahl[buf][0][1][0][lane][0];
            const f16x8 a1l = *(const f16x8*)&Ahl[buf][0][1][1][lane][0];
            acc0 = __builtin_amdgcn_mfma_f32_32x32x16_f16(a0h, bh0, acc0, 0, 0, 0);
            acc1 = __builtin_amdgcn_mfma_f32_32x32x16_f16(a1h, bh0, acc1, 0, 0, 0);
            acc0 = __builtin_amdgcn_mfma_f32_32x32x16_f16(a0h, bl0, acc0, 0, 0, 0);
            acc1 = __builtin_amdgcn_mfma_f32_32x32x16_f16(a1h, bl0, acc1, 0, 0, 0);
            acc0 = __builtin_amdgcn_mfma_f32_32x32x16_f16(a0l, bh0, acc0, 0, 0, 0);
            acc1 = __builtin_amdgcn_mfma_f32_32x32x16_f16(a1l, bh0, acc1, 0, 0, 0);
        }
        {
            const f16x8 a0h = *(const f16x8*)&Ahl[buf][1][0][0][lane][0];
            const f16x8 a0l = *(const f16x8*)&Ahl[buf][1][0][1][lane][0];
            const f16x8 a1h = *(const f16x8*)&Ahl[buf][1][1][0][lane][0];
            const f16x8 a1l = *(const f16x8*)&Ahl[buf][1][1][1][lane][0];
            acc0 = __builtin_amdgcn_mfma_f32_32x32x16_f16(a0h, bh1, acc0, 0, 0, 0);
            acc1 = __builtin_amdgcn_mfma_f32_32x32x16_f16(a1h, bh1, acc1, 0, 0, 0);
            acc0 = __builtin_amdgcn_mfma_f32_32x32x16_f16(a0h, bl1, acc0, 0, 0, 0);
            acc1 = __builtin_amdgcn_mfma_f32_32x32x16_f16(a1h, bl1, acc1, 0, 0, 0);
            acc0 = __builtin_amdgcn_mfma_f32_32x32x16_f16(a0l, bh1, acc0, 0, 0, 0);
            acc1 = __builtin_amdgcn_mfma_f32_32x32x16_f16(a1l, bh1, acc1, 0, 0, 0);
        }
        // ---- stage next chunk into the other buffer ----
        if (has_next) {
            f16x4 h, l;
            const float* v = (const float*)&xn;
#pragma unroll
            for (int u = 0; u < 4; ++u) {
                const f16 hh = (f16)v[u];
                h[u] = hh; l[u] = (f16)(v[u] - (float)hh);
            }
            *(f16x4*)&Ahl[buf ^ 1][s_kh][s_tile][0][s_lane][s_j] = h;
            *(f16x4*)&Ahl[buf ^ 1][s_kh][s_tile][1][s_lane][s_j] = l;
            bh0 = nbh0; bl0 = nbl0; bh1 = nbh1; bl1 = nbl1;
        }
        __syncthreads();
        buf ^= 1;
    }

    // ---- epilogue: C/D layout col=lane&31, row=(r&3)+8*(r>>2)+4*(lane>>5) ----
    const int ccol  = wv * 32 + (lane & 31);
    const int rbase = 4 * (lane >> 5);
#pragma unroll
    for (int r = 0; r < 16; ++r) {
        const int rw = (r & 3) + 8 * (r >> 2) + rbase;
        Sc[rw * 257 + ccol]        = acc0[r];
        Sc[(rw + 32) * 257 + ccol] = acc1[r];
    }
    __syncthreads();

    // ---- routing: one lane per row ----
    if (tid < 64) {
        float* sc = &Sc[tid * 257];
        for (int e = 0; e < E; ++e)
            sc[e] = 1.0f / (1.0f + expf(-sc[e] * INV_W_SCALE));
        const int token = row0 + tid;
        const float mingap = route_row(sc, out + (size_t)token * TOPK,
                                       out + (size_t)T * TOPK + (size_t)token * TOPK);
        if (mingap < EPS_GAP) {
            const int s = atomicAdd(cnt, 1);
            if (s < T) list[s] = token;
        }
    }
}

// ---------------------------------------------------------------------------
// Phase 3: exact fp32 recompute + routing for flagged (near-tie) tokens.
// Round-0 structure (proven: VGPR=44, zero scratch) with ONE change:
// FNT=4 full token rows staged in LDS (114.7 KB) so each W stream is
// amortized over 4 tokens -> W L2 traffic / 4.  No double-buffering, no
// per-chunk barriers, tiny static register state -> no spill risk
// (round-2's 3 GB scratch-writeback failure mode).
// Per-expert summation order (sequential 64-float c2 chunks over full D,
// identical FMA expression) EXACTLY matches round 0 -> numerics unchanged.
// ---------------------------------------------------------------------------
__global__ __launch_bounds__(256)
void gate_fixup(const float* __restrict__ X, const float* __restrict__ W,
                float* __restrict__ out, const int* __restrict__ cnt,
                const int* __restrict__ list) {
    __shared__ float xs[FNT][D];        // 114.7 KB: 4 full token rows
    __shared__ float sc[FNT][E + 1];    // 4.1 KB scores
    int n = *cnt; if (n > T) n = T;
    if (n <= 0) return;
    const int e = threadIdx.x;
    const float* wr = W + (size_t)e * D;
    const int g = threadIdx.x >> 6;     // token slot this wave stages (0..3)
    const int l = threadIdx.x & 63;     // lane within wave

    for (int base = blockIdx.x * FNT; base < n; base += gridDim.x * FNT) {
        // ---- coalesced stage: wave g loads full row of token slot g ----
        int sidx = base + g; if (sidx > n - 1) sidx = n - 1;   // tail: dup, benign
        const float* xr = X + (size_t)list[sidx] * D;
#pragma unroll
        for (int j = 0; j < D / 256; ++j) {          // 28 float4 per thread
            const int q = (j * 64 + l) * 4;
            *(float4*)&xs[g][q] = *(const float4*)&xr[q];
        }
        __syncthreads();

        // ---- thread e: exact fp32 dot vs 4 tokens, W streamed once ----
        float acc[FNT] = {0.0f, 0.0f, 0.0f, 0.0f};
        for (int c0 = 0; c0 < D; c0 += 64) {
            float c2[FNT] = {0.0f, 0.0f, 0.0f, 0.0f};
#pragma unroll
            for (int k = 0; k < 64; k += 4) {
                const float4 wv = *(const float4*)&wr[c0 + k];
#pragma unroll
                for (int t = 0; t < FNT; ++t) {
                    const float4 xv = *(const float4*)&xs[t][c0 + k];
                    c2[t] += xv.x * wv.x + xv.y * wv.y + xv.z * wv.z + xv.w * wv.w;
                }
            }
#pragma unroll
            for (int t = 0; t < FNT; ++t) acc[t] += c2[t];
        }

#pragma unroll
        for (int t = 0; t < FNT; ++t)
            sc[t][e] = 1.0f / (1.0f + expf(-acc[t]));
        __syncthreads();
        if (e < FNT && base + e < n) {
            const int tok = list[base + e];
            route_row(&sc[e][0], out + (size_t)tok * TOPK,
                      out + (size_t)T * TOPK + (size_t)tok * TOPK);
        }
        __syncthreads();   // protect sc/xs from next iteration's writers
    }
}

// ---------------------------------------------------------------------------
// Fallback (round-2 fp32 vector kernel) if ws is too small for Bpack
// ---------------------------------------------------------------------------
__global__ __launch_bounds__(256, 2)
void gate_fused_fp32(const float* __restrict__ X, const float* __restrict__ W,
                     float* __restrict__ out) {
    constexpr int BM = 32, BK = 16, AS_S = 36, BS_S = 260, SC_S = 257;
    __shared__ float As[BK * AS_S];
    __shared__ float Bs[BK * BS_S];
    __shared__ float Sc[BM * SC_S];

    const int tid  = threadIdx.x;
    const int row0 = blockIdx.x * BM;
    const int lrow = tid >> 2;
    const int kq4  = (tid & 3) << 2;
    const bool a_loader = (tid < 128);

    const float* aptr = X + (size_t)(row0 + (lrow & 31)) * D + kq4;
    const float* bptr = W + (size_t)lrow * D + kq4;
    const int ty = tid >> 5, tx = tid & 31;

    float acc[4][8];
#pragma unroll
    for (int i = 0; i < 4; ++i)
#pragma unroll
        for (int j = 0; j < 8; ++j) acc[i][j] = 0.0f;

    float4 areg;
    if (a_loader) areg = *(const float4*)aptr;
    float4 breg0 = *(const float4*)(bptr);
    float4 breg1 = *(const float4*)(bptr + (size_t)64 * D);
    float4 breg2 = *(const float4*)(bptr + (size_t)128 * D);
    float4 breg3 = *(const float4*)(bptr + (size_t)192 * D);
    aptr += BK; bptr += BK;

    constexpr int NKT = D / BK;
    for (int kt = 0; kt < NKT; ++kt) {
        __syncthreads();
        {
            const float* b0 = (const float*)&breg0;
            const float* b1 = (const float*)&breg1;
            const float* b2 = (const float*)&breg2;
            const float* b3 = (const float*)&breg3;
#pragma unroll
            for (int j = 0; j < 4; ++j) {
                Bs[(kq4 + j) * BS_S + lrow]       = b0[j];
                Bs[(kq4 + j) * BS_S + 64 + lrow]  = b1[j];
                Bs[(kq4 + j) * BS_S + 128 + lrow] = b2[j];
                Bs[(kq4 + j) * BS_S + 192 + lrow] = b3[j];
            }
            if (a_loader) {
                const float* a = (const float*)&areg;
#pragma unroll
                for (int j = 0; j < 4; ++j)
                    As[(kq4 + j) * AS_S + (lrow & 31)] = a[j];
            }
        }
        __syncthreads();
        if (kt + 1 < NKT) {
            if (a_loader) areg = *(const float4*)aptr;
            breg0 = *(const float4*)(bptr);
            breg1 = *(const float4*)(bptr + (size_t)64 * D);
            breg2 = *(const float4*)(bptr + (size_t)128 * D);
            breg3 = *(const float4*)(bptr + (size_t)192 * D);
            aptr += BK; bptr += BK;
        }
        float c2[4][8];
#pragma unroll
        for (int k = 0; k < BK; ++k) {
            float af[4], bf[8];
            *(float4*)&af[0] = *(const float4*)&As[k * AS_S + (ty << 2)];
            *(float4*)&bf[0] = *(const float4*)&Bs[k * BS_S + (tx << 2)];
            *(float4*)&bf[4] = *(const float4*)&Bs[k * BS_S + 128 + (tx << 2)];
#pragma unroll
            for (int i = 0; i < 4; ++i)
#pragma unroll
                for (int j = 0; j < 8; ++j) {
                    if (k == 0) c2[i][j] = af[i] * bf[j];
                    else        c2[i][j] += af[i] * bf[j];
                }
        }
#pragma unroll
        for (int i = 0; i < 4; ++i)
#pragma unroll
            for (int j = 0; j < 8; ++j) acc[i][j] += c2[i][j];
    }

    __syncthreads();
#pragma unroll
    for (int i = 0; i < 4; ++i) {
        const int r = (ty << 2) + i;
#pragma unroll
        for (int j = 0; j < 8; ++j) {
            const int c = (j < 4) ? ((tx << 2) + j) : (128 + (tx << 2) + j - 4);
            Sc[r * SC_S + c] = acc[i][j];
        }
    }
    __syncthreads();

    if (tid < BM) {
        float* sc = &Sc[tid * SC_S];
        for (int e = 0; e < E; ++e) sc[e] = 1.0f / (1.0f + expf(-sc[e]));
        const int token = row0 + tid;
        route_row(sc, out + (size_t)token * TOPK,
                  out + (size_t)T * TOPK + (size_t)token * TOPK);
    }
}

extern "C" void kernel_launch(void* const* d_in, const int* in_sizes, int n_in,
                              void* d_out, int out_size, void* d_ws, size_t ws_size,
                              hipStream_t stream) {
    const float* x = (const float*)d_in[0];
    const float* w = (const float*)d_in[1];
    float* out = (float*)d_out;
    (void)in_sizes; (void)n_in; (void)out_size;

    if (ws_size >= WS_NEEDED) {
        int* cnt   = (int*)((char*)d_ws + WS_CNT);
        int* list  = (int*)((char*)d_ws + WS_LIST);
        f16* bpack = (f16*)((char*)d_ws + WS_BPACK);
        zero_cnt<<<1, 64, 0, stream>>>(cnt);
        pack_w<<<896, 256, 0, stream>>>(w, bpack);
        gate_mfma<<<T / 64, 512, 0, stream>>>(x, bpack, out, cnt, list);
        gate_fixup<<<1024, 256, 0, stream>>>(x, w, out, cnt, list);
    } else {
        gate_fused_fp32<<<T / 32, 256, 0, stream>>>(x, w, out);
    }
}